// Round 10
// baseline (230.655 us; speedup 1.0000x reference)
//
#include <hip/hip_runtime.h>
#include <hip/hip_bf16.h>
#include <cstdint>

// B=2, HW=64 -> 128 rows of S=256; M = 32768. D=512, HEADS=8, DK=64,
// 3*H*DK=1536, KSIZE=7. Inputs/outputs fp32; internal compute bf16 MFMA.
//
// Round-10: the fused kernel gets a DEPTH-1 READ PIPELINE (reads of tile t+1
// issued under MFMA of tile t) on top of a depth-3 DMA prefetch (quad-buffered
// LDS). Rationale: 2-block/CU GEMMs measured ~90% DS-pipe utilization; all
// 1-block/CU variants measure ~45% because each tile's ds_reads are issued and
// immediately waited (convoy). Pipelining the reads one tile deep fills the
// DS pipe without needing a second resident block.

typedef __bf16 bf16x8 __attribute__((ext_vector_type(8)));
typedef float f32x4 __attribute__((ext_vector_type(4)));

__device__ __forceinline__ uint16_t f2bf(float f) {
    uint32_t u = __builtin_bit_cast(uint32_t, f);
    return (uint16_t)((u + 0x7fffu + ((u >> 16) & 1u)) >> 16);
}
__device__ __forceinline__ float bflo(uint32_t u) { return __builtin_bit_cast(float, u << 16); }
__device__ __forceinline__ float bfhi(uint32_t u) { return __builtin_bit_cast(float, u & 0xffff0000u); }

__device__ __forceinline__ void unpack8(uint4 v, float* f) {
    f[0] = bflo(v.x); f[1] = bfhi(v.x);
    f[2] = bflo(v.y); f[3] = bfhi(v.y);
    f[4] = bflo(v.z); f[5] = bfhi(v.z);
    f[6] = bflo(v.w); f[7] = bfhi(v.w);
}
__device__ __forceinline__ uint32_t pack2(float a, float b) {
    return (uint32_t)f2bf(a) | ((uint32_t)f2bf(b) << 16);
}

#define GLOAD_LDS16(gp, lp)                                                        \
    __builtin_amdgcn_global_load_lds((const __attribute__((address_space(1))) void*)(gp), \
                                     (__attribute__((address_space(3))) void*)(lp), 16, 0, 0)

// Inline-asm LDS read: invisible to compiler waitcnt/alias tracking; caller
// owns lgkmcnt discipline (wait + sched_barrier(0) before consuming MFMAs).
__device__ __forceinline__ bf16x8 ds_read16(const uint16_t* p) {
    bf16x8 r;
    asm volatile("ds_read_b128 %0, %1"
                 : "=v"(r)
                 : "v"((const __attribute__((address_space(3))) void*)p));
    return r;
}

// ---------------------------------------------------------------------------
// prep: fp32->bf16 bulk convert of X (blocks [0,8192)) + both weight
// transposes (blocks [8192,12288)) in ONE dispatch.
// ---------------------------------------------------------------------------
__global__ void prep(const float* __restrict__ X, const float* __restrict__ Wqkv,
                     const float* __restrict__ Wout, uint16_t* __restrict__ Xb,
                     uint16_t* __restrict__ WqkvT, uint16_t* __restrict__ WoutT) {
    int b = blockIdx.x;
    if (b < 8192) {
        int i = b * 256 + threadIdx.x;
        const float4* p = (const float4*)X + (size_t)i * 2;
        float4 a = p[0], q = p[1];
        uint4 o;
        o.x = pack2(a.x, a.y);
        o.y = pack2(a.z, a.w);
        o.z = pack2(q.x, q.y);
        o.w = pack2(q.z, q.w);
        *((uint4*)Xb + i) = o;
    } else {
        int idx = (b - 8192) * 256 + threadIdx.x;
        if (idx < 512 * 1536) {
            int r = idx / 1536, c = idx - r * 1536;
            WqkvT[(size_t)c * 512 + r] = f2bf(Wqkv[idx]);
        } else {
            idx -= 512 * 1536;
            int r = idx >> 9, c = idx & 511;
            WoutT[(size_t)c * 512 + r] = f2bf(Wout[idx]);
        }
    }
}

// ---------------------------------------------------------------------------
// FUSED qkv-projection + local-window attention, pipelined reads.
// Block = (bn, head): id = h*128 + bn. 512 threads = 8 waves (4 M x 2 N),
// wave tile 64x96, acc[4][6] (96 regs), BK=32, NT=16 (K=512).
//
// LDS (uint16 elems): A bufs 4 x 8192 [0,32768); B bufs 4 x 6144
// [32768,57344). Attn union (GEMM phase done): Q [0,16384), K [16384,33152),
// V [33152,49920), P(f32) [49920,54016). Total 57344 elems = 114.7 KB,
// 1 block/CU.
//
// Staging (wave-uniform): waves 0-3 stage the 1024 A-chunks (4 instr each),
// waves 4-6 the 768 B-chunks, wave 7 none (its vmcnt waits are free no-ops).
// Per-instruction LDS dest is wave-uniform-base + lane*16 (DMA constraint);
// XOR swizzle (packed-2-rows layout) applied to the global source address.
//
// Per-tile schedule (body t):
//   1. issue reads(t+1) from buf[(t+1)&3]  [stage(t+1) certified at body(t-1)]
//   2. lgkmcnt(10)  -> reads(t) drained (issued one tile ago; wait ~free)
//   3. 24 MFMA on tile-t frags  [reads(t+1) retire underneath]
//   4. stage(t+3) -> buf[(t+3)&3]  [= buf[(t-1)&3]; its readers drained at
//      body(t-1) step2 and certified by body(t-1)'s barrier]
//   5. vmcnt(4)  -> stage(t+2) landed, stage(t+3) in flight (never 0 mid-loop)
//   6. barrier   [publishes t+1-landed + reads(t)-drained to all waves]
// ---------------------------------------------------------------------------
__global__ __launch_bounds__(512, 2)
void gemm_qkv_attn(const uint16_t* __restrict__ Xb, const uint16_t* __restrict__ WqkvT,
                   const float* __restrict__ pb, uint16_t* __restrict__ attn) {
    __shared__ __align__(16) uint16_t lds[57344];  // 114.7 KB

    constexpr int KO = 16384;   // attn K array (elems)
    constexpr int VO = 33152;   // attn V array
    constexpr int PO = 49920;   // attn partial/p f32 buffer

    const int tid  = threadIdx.x;
    const int lane = tid & 63;
    const int wv   = tid >> 6;
    const int r    = lane & 15;
    const int quad = lane >> 4;
    const int wr   = wv >> 1;   // 0..3  (M wave)
    const int wc   = wv & 1;    // 0..1  (N wave)
    const int h    = blockIdx.x >> 7;
    const int bn   = blockIdx.x & 127;
    const long bm0 = (long)bn * 256;

    // ---- staging sources: 4 chunks per thread (waves 0-6), inverse swizzle ----
    const uint16_t* srcp[4];
    int rel[4];
#pragma unroll
    for (int i = 0; i < 4; ++i) {
        int j = wv * 256 + i * 64 + lane;       // global chunk id 0..1791
        if (j < 1024) {                          // A chunk
            int d = j, ln = d >> 3, pre = (d & 7) ^ (ln & 7);
            int row = 2 * ln + (pre >> 2), col = (pre & 3) * 8;
            srcp[i] = Xb + (bm0 + row) * 512L + col;
            rel[i]  = d * 8;
        } else {                                 // B chunk
            int e = j - 1024, ln = e >> 3, pre = (e & 7) ^ (ln & 7);
            int row = 2 * ln + (pre >> 2), col = (pre & 3) * 8;
            long grow = ((long)(row >> 6)) * 512 + h * 64 + (row & 63);
            srcp[i] = WqkvT + grow * 512 + col;
            rel[i]  = e * 8;
        }
    }

#define STAGE(q_, t_) do {                                                              \
        if (wv < 4) {                                                                   \
            _Pragma("unroll")                                                           \
            for (int i_ = 0; i_ < 4; ++i_)                                              \
                GLOAD_LDS16(srcp[i_] + (t_) * 32, &lds[(q_) * 8192 + rel[i_]]);         \
        } else if (wv < 7) {                                                            \
            _Pragma("unroll")                                                           \
            for (int i_ = 0; i_ < 4; ++i_)                                              \
                GLOAD_LDS16(srcp[i_] + (t_) * 32, &lds[32768 + (q_) * 6144 + rel[i_]]); \
        }                                                                               \
    } while (0)

    // ---- compute-side lane constants (packed-2-rows XOR layout) ----
    const int p_ln  = (((r & 1) << 2) | quad) ^ ((r >> 1) & 7);
    const int aLane = wr * 2048 + (r >> 1) * 64 + p_ln * 8;   // + mf*512
    const int bLane = wc * 3072 + (r >> 1) * 64 + p_ln * 8;   // + nf*512 (B area rel)

    f32x4 acc[4][6];
#pragma unroll
    for (int mf = 0; mf < 4; ++mf)
#pragma unroll
        for (int nf = 0; nf < 6; ++nf) acc[mf][nf] = (f32x4){0.f, 0.f, 0.f, 0.f};

    bf16x8 fA0[4], fB0[6], fA1[4], fB1[6];

#define READS(q_, FA_, FB_) do {                                                        \
        const int ao_ = (q_) * 8192, bo_ = 32768 + (q_) * 6144;                         \
        _Pragma("unroll")                                                               \
        for (int nf_ = 0; nf_ < 6; ++nf_) FB_[nf_] = ds_read16(&lds[bo_ + bLane + nf_ * 512]); \
        _Pragma("unroll")                                                               \
        for (int mf_ = 0; mf_ < 4; ++mf_) FA_[mf_] = ds_read16(&lds[ao_ + aLane + mf_ * 512]); \
    } while (0)

#define BODY(t_, FAn_, FBn_, FAc_, FBc_) do {                                           \
        if ((t_) + 1 < 16) {                                                            \
            READS(((t_) + 1) & 3, FAn_, FBn_);                                          \
            asm volatile("s_waitcnt lgkmcnt(10)" ::: "memory");                         \
        } else {                                                                        \
            asm volatile("s_waitcnt lgkmcnt(0)" ::: "memory");                          \
        }                                                                               \
        __builtin_amdgcn_sched_barrier(0);                                              \
        __builtin_amdgcn_s_setprio(1);                                                  \
        _Pragma("unroll")                                                               \
        for (int nf_ = 0; nf_ < 6; ++nf_)                                               \
            _Pragma("unroll")                                                           \
            for (int mf_ = 0; mf_ < 4; ++mf_)                                           \
                acc[mf_][nf_] = __builtin_amdgcn_mfma_f32_16x16x32_bf16(                \
                    FBc_[nf_], FAc_[mf_], acc[mf_][nf_], 0, 0, 0);                      \
        __builtin_amdgcn_s_setprio(0);                                                  \
        if ((t_) + 3 < 16) {                                                            \
            STAGE(((t_) + 3) & 3, (t_) + 3);                                            \
            asm volatile("s_waitcnt vmcnt(4)" ::: "memory");                            \
        } else {                                                                        \
            asm volatile("s_waitcnt vmcnt(0)" ::: "memory");                            \
        }                                                                               \
        if ((t_) < 15) __builtin_amdgcn_s_barrier();                                    \
    } while (0)

    // ---- prologue: stage tiles 0,1,2; certify 0 and 1; read tile 0 ----
    STAGE(0, 0);
    STAGE(1, 1);
    STAGE(2, 2);
    asm volatile("s_waitcnt vmcnt(4)" ::: "memory");   // stage0,1 landed; stage2 in flight
    __builtin_amdgcn_s_barrier();
    READS(0, fA0, fB0);

    for (int tt = 0; tt < 16; tt += 2) {
        BODY(tt,     fA1, fB1, fA0, fB0);   // reads(tt+1) -> set1, MFMA tile tt from set0
        BODY(tt + 1, fA0, fB0, fA1, fB1);   // reads(tt+2) -> set0, MFMA tile tt+1 from set1
    }

    // ---- all DMA/reads drained; barrier before overwriting LDS for attn ----
    asm volatile("s_waitcnt vmcnt(0) lgkmcnt(0)" ::: "memory");
    __builtin_amdgcn_s_barrier();

    // ---- zero-fill K/V halo rows (0,1,2,259,260,261) ----
    if (tid < 96) {
        int a    = tid / 48;
        int rem  = tid - a * 48;
        int hr6  = rem >> 3;
        int c8   = rem & 7;
        int hrow = (hr6 < 3) ? hr6 : (256 + hr6);
        ((uint4*)&lds[a ? VO : KO])[hrow * 8 + c8] = (uint4){0u, 0u, 0u, 0u};
    }

    // ---- spill acc (C^T frags: m = r, n = quad*4 + reg) -> attn layout ----
#pragma unroll
    for (int nf = 0; nf < 6; ++nf) {
        int arr, d0;
        if (wc == 0) { if (nf < 4) { arr = 0; d0 = nf * 16; } else { arr = 1; d0 = (nf - 4) * 16; } }
        else         { if (nf < 2) { arr = 1; d0 = 32 + nf * 16; } else { arr = 2; d0 = (nf - 2) * 16; } }
        const int base = (arr == 0) ? 0 : ((arr == 1) ? KO : VO);
        const int hofs = (arr == 0) ? 0 : 3;
        const int cc0  = (d0 >> 3) + (quad >> 1);   // 16B-chunk index of this quad's d
        const int sub  = (quad & 1) * 4;            // elem offset within chunk
#pragma unroll
        for (int mf = 0; mf < 4; ++mf) {
            int rowX = wr * 64 + mf * 16 + r + hofs;
            uint2 w;
            w.x = pack2(acc[mf][nf][0], acc[mf][nf][1]);
            w.y = pack2(acc[mf][nf][2], acc[mf][nf][3]);
            *(uint2*)&lds[base + rowX * 64 + ((cc0 ^ (rowX & 7)) << 3) + sub] = w;
        }
    }
    __syncthreads();

    // ================= attention phase =================
    const int s     = tid & 255;
    const int half  = tid >> 8;
    const int cbase = half * 4;
    float* pp = (float*)&lds[PO];   // [256][8] f32

    uint4 qc[4];
    const uint4* qarr = (const uint4*)lds;
#pragma unroll
    for (int c = 0; c < 4; ++c) qc[c] = qarr[s * 8 + ((cbase + c) ^ (s & 7))];

    float sc[7];
#pragma unroll
    for (int w = 0; w < 7; ++w) sc[w] = 0.f;
    const uint4* karr = (const uint4*)&lds[KO];
#pragma unroll
    for (int c = 0; c < 4; ++c) {
        float qf[8];
        unpack8(qc[c], qf);
#pragma unroll
        for (int w = 0; w < 7; ++w) {
            int hrow = s + w;
            uint4 kc = karr[hrow * 8 + ((cbase + c) ^ (hrow & 7))];
            float kf[8];
            unpack8(kc, kf);
#pragma unroll
            for (int j = 0; j < 8; ++j) sc[w] += qf[j] * kf[j];
        }
    }

    if (half == 1) {
#pragma unroll
        for (int w = 0; w < 7; ++w) pp[s * 8 + w] = sc[w];
    }
    __syncthreads();

    if (half == 0) {
        const float* pbr = pb + ((size_t)h * 256 + s) * 7;
        float mx = -1e30f, tot[7];
#pragma unroll
        for (int w = 0; w < 7; ++w) {
            tot[w] = (sc[w] + pp[s * 8 + w]) * 0.125f + pbr[w];
            mx = fmaxf(mx, tot[w]);
        }
        float sum = 0.f;
#pragma unroll
        for (int w = 0; w < 7; ++w) {
            tot[w] = __expf(tot[w] - mx);
            sum += tot[w];
        }
        const float inv = 1.f / sum;
#pragma unroll
        for (int w = 0; w < 7; ++w) pp[s * 8 + w] = tot[w] * inv;
    }
    __syncthreads();

    float p[7];
#pragma unroll
    for (int w = 0; w < 7; ++w) p[w] = pp[s * 8 + w];

    const uint4* varr = (const uint4*)&lds[VO];
    uint4 ov[4];
#pragma unroll
    for (int c = 0; c < 4; ++c) {
        float o[8] = {0.f, 0.f, 0.f, 0.f, 0.f, 0.f, 0.f, 0.f};
#pragma unroll
        for (int w = 0; w < 7; ++w) {
            int hrow = s + w;
            uint4 vc = varr[hrow * 8 + ((cbase + c) ^ (hrow & 7))];
            float vf[8];
            unpack8(vc, vf);
#pragma unroll
            for (int j = 0; j < 8; ++j) o[j] += p[w] * vf[j];
        }
        ov[c].x = pack2(o[0], o[1]);
        ov[c].y = pack2(o[2], o[3]);
        ov[c].z = pack2(o[4], o[5]);
        ov[c].w = pack2(o[6], o[7]);
    }
    uint16_t* orow = attn + ((size_t)(bn * 256 + s)) * 512 + h * 64 + cbase * 8;
#pragma unroll
    for (int c = 0; c < 4; ++c) *(uint4*)(orow + c * 8) = ov[c];
#undef STAGE
#undef READS
#undef BODY
}

// ---------------------------------------------------------------------------
// 256x128-tile bf16 GEMM (round-6 pipeline, swapped-operand MFMA -> C^T
// frags, contiguous dwordx4 stores). Output projection.
// ---------------------------------------------------------------------------
template <bool F32OUT>
__global__ __launch_bounds__(512, 4)
void gemm_mn(const uint16_t* __restrict__ A, const uint16_t* __restrict__ BT,
             void* __restrict__ Cout, int M, int N, int K) {
    __shared__ __align__(16) uint16_t lds[36864];  // 72 KB (3 bufs)

    const int tid  = threadIdx.x;
    const int lane = tid & 63;
    const int wv   = tid >> 6;
    const int r    = lane & 15;
    const int quad = lane >> 4;
    const int wr   = wv >> 1;
    const int wc   = wv & 1;
    const long bm0 = (long)blockIdx.x * 256;
    const long bn0 = (long)blockIdx.y * 128;
    const int NT   = K >> 5;

#define SRC_ROWCOL(d_, row_, col_) do {                                                 \
        int ln_ = (d_) >> 3, pre_ = ((d_) & 7) ^ (ln_ & 7);                             \
        row_ = 2 * ln_ + (pre_ >> 2);                                                   \
        col_ = (pre_ & 3) * 8;                                                          \
    } while (0)
    int rA0, cA0, rA1, cA1, rB0, cB0;
    SRC_ROWCOL(tid,       rA0, cA0);
    SRC_ROWCOL(tid + 512, rA1, cA1);
    SRC_ROWCOL(tid,       rB0, cB0);
    const uint16_t* pA0 = A  + (bm0 + rA0) * (long)K + cA0;
    const uint16_t* pA1 = A  + (bm0 + rA1) * (long)K + cA1;
    const uint16_t* pB0 = BT + (bn0 + rB0) * (long)K + cB0;
#undef SRC_ROWCOL

#define STAGE(b_, t_) do {                                                              \
        GLOAD_LDS16(pA0 + (t_) * 32, &lds[(b_) * 8192 + tid * 8]);                      \
        GLOAD_LDS16(pA1 + (t_) * 32, &lds[(b_) * 8192 + (tid + 512) * 8]);              \
        GLOAD_LDS16(pB0 + (t_) * 32, &lds[24576 + (b_) * 4096 + tid * 8]);              \
    } while (0)

    const int p_ln  = (((r & 1) << 2) | quad) ^ ((r >> 1) & 7);
    const int aLane = wr * 2048 + (r >> 1) * 64 + p_ln * 8;
    const int bLane = 24576 + wc * 2048 + (r >> 1) * 64 + p_ln * 8;

#define DS_A(mf_) ds_read16(&lds[aoff + aLane + (mf_) * 512])
#define DS_B(nf_) ds_read16(&lds[boff + bLane + (nf_) * 512])
#define WAITK2 do { asm volatile("s_waitcnt lgkmcnt(2)" ::: "memory");                  \
                    __builtin_amdgcn_sched_barrier(0); } while (0)
#define WAITK0 do { asm volatile("s_waitcnt lgkmcnt(0)" ::: "memory");                  \
                    __builtin_amdgcn_sched_barrier(0); } while (0)
#define MFMA_CL(m0_, f0_, f1_)                                                          \
    __builtin_amdgcn_s_setprio(1);                                                      \
    _Pragma("unroll")                                                                   \
    for (int nf = 0; nf < 4; ++nf)                                                      \
        acc[(m0_)][nf] = __builtin_amdgcn_mfma_f32_16x16x32_bf16(bfr[nf], f0_,          \
                                                                 acc[(m0_)][nf], 0, 0, 0); \
    _Pragma("unroll")                                                                   \
    for (int nf = 0; nf < 4; ++nf)                                                      \
        acc[(m0_) + 1][nf] = __builtin_amdgcn_mfma_f32_16x16x32_bf16(bfr[nf], f1_,      \
                                                                 acc[(m0_) + 1][nf], 0, 0, 0); \
    __builtin_amdgcn_s_setprio(0);

    f32x4 acc[4][4];
#pragma unroll
    for (int mf = 0; mf < 4; ++mf)
#pragma unroll
        for (int nf = 0; nf < 4; ++nf) acc[mf][nf] = (f32x4){0.f, 0.f, 0.f, 0.f};

    STAGE(0, 0);
    STAGE(1, 1);
    asm volatile("s_waitcnt vmcnt(3)" ::: "memory");
    __builtin_amdgcn_s_barrier();

    int b = 0, bs = 2;
    for (int t = 0; t < NT; ++t) {
        const int aoff = b * 8192;
        const int boff = b * 4096;

        if (t + 2 < NT) STAGE(bs, t + 2);

        bf16x8 bfr[4], a0, a1, a2, a3;
#pragma unroll
        for (int nf = 0; nf < 4; ++nf) bfr[nf] = DS_B(nf);
        a0 = DS_A(0); a1 = DS_A(1);
        a2 = DS_A(2); a3 = DS_A(3);

        WAITK2;
        MFMA_CL(0, a0, a1)
        WAITK0;
        MFMA_CL(2, a2, a3)

        if (t + 1 < NT) {
            if (t + 2 < NT)
                asm volatile("s_waitcnt vmcnt(3)" ::: "memory");
            else
                asm volatile("s_waitcnt vmcnt(0)" ::: "memory");
            __builtin_amdgcn_s_barrier();
        }
        b  = (b  == 2) ? 0 : b + 1;
        bs = (bs == 2) ? 0 : bs + 1;
    }

#pragma unroll
    for (int mf = 0; mf < 4; ++mf) {
        long m = bm0 + wr * 64 + mf * 16 + r;
#pragma unroll
        for (int nf = 0; nf < 4; ++nf) {
            long n0 = bn0 + wc * 64 + nf * 16 + quad * 4;
            if (F32OUT) {
                float4 v = {acc[mf][nf][0], acc[mf][nf][1], acc[mf][nf][2], acc[mf][nf][3]};
                *(float4*)((float*)Cout + m * (long)N + n0) = v;
            } else {
                uint2 w;
                w.x = pack2(acc[mf][nf][0], acc[mf][nf][1]);
                w.y = pack2(acc[mf][nf][2], acc[mf][nf][3]);
                *(uint2*)((uint16_t*)Cout + m * (long)N + n0) = w;
            }
        }
    }
#undef STAGE
#undef DS_A
#undef DS_B
#undef WAITK2
#undef WAITK0
#undef MFMA_CL
}

// ---------------------------------------------------------------------------
extern "C" void kernel_launch(void* const* d_in, const int* in_sizes, int n_in,
                              void* d_out, int out_size, void* d_ws, size_t ws_size,
                              hipStream_t stream) {
    const float* X    = (const float*)d_in[0];  // 32768 x 512 fp32
    const float* pb   = (const float*)d_in[1];  // 8 x 256 x 7 fp32
    const float* Wqkv = (const float*)d_in[2];  // 512 x 1536 fp32
    const float* Wout = (const float*)d_in[3];  // 512 x 512 fp32
    float* out = (float*)d_out;                 // 32768 x 512 fp32

    char* ws = (char*)d_ws;
    uint16_t* WqkvT = (uint16_t*)(ws);                  // 1536x512 bf16 = 1.5 MB
    uint16_t* WoutT = (uint16_t*)(ws + 1572864);        // 512x512  bf16 = 0.5 MB
    uint16_t* Xb    = (uint16_t*)(ws + 2097152);        // 32768x512 bf16 = 32 MB
    uint16_t* attnb = (uint16_t*)(ws + 35651584);       // 32768x512 bf16 = 32 MB

    prep<<<12288, 256, 0, stream>>>(X, Wqkv, Wout, Xb, WqkvT, WoutT);
    gemm_qkv_attn<<<1024, 512, 0, stream>>>(Xb, WqkvT, pb, attnb);
    gemm_mn<true><<<dim3(128, 4), 512, 0, stream>>>(attnb, WoutT, out, 32768, 512, 512);
}